// Round 1
// baseline (206.088 us; speedup 1.0000x reference)
//
#include <hip/hip_runtime.h>
#include <math.h>

// BioTripletLoss: B=16384 rows, D=1024 fp32.
// pos_dist[i] = ||h[i]+r[i]-t[i]||, neg_dist[i] = ||h[i]+r[i]-t[neg_idx[i]]||
// dissim (rel==1): relu(0.6 - pos) + 0.5*exp(-pos)
// sim:             relu(pos - neg + 0.3) + 0.3*relu(0.1 - pos)
// out = mean(per_sample)
//
// R8: max-MLP VGPR-path version. Theory: R7's 78us = 3.44 TB/s logical read
// rate, limited by in-flight bytes / latency (Little's law), NOT by DRAM
// (time was invariant to L3-vs-HBM residency) and NOT by the load-path
// itself (m97 GEMM sustains ~21 B/cy/CU through the same path at L2-hit
// latency). R7 structurally capped MLP: LDS-capped 30% occupancy x only
// 4-8KB in flight per wave, with a full vmcnt drain every 4KB chunk.
// Here: no LDS staging at all; each wave issues all 16 global_load_dwordx4
// (16KB) back-to-back, then consumes. ~100 VGPR -> 16 waves/CU, 256KB
// nominal in-flight per CU.

#define BDIM 16384
#define DDIM 1024

typedef float vfloat4 __attribute__((ext_vector_type(4)));

__global__ void zero_out_kernel(float* __restrict__ out) { out[0] = 0.0f; }

__global__ __launch_bounds__(256, 4) void triplet_vgpr_kernel(
    const float* __restrict__ h, const float* __restrict__ t,
    const float* __restrict__ r, const int* __restrict__ rel,
    const int* __restrict__ neg, float* __restrict__ out)
{
    __shared__ float sm[4];

    const int wave = threadIdx.x >> 6;
    const int lane = threadIdx.x & 63;
    const int row  = (blockIdx.x << 2) + wave;

    const int nidx = neg[row];
    const int rl   = rel[row];

    // dissim rows never use neg_dist: alias gather to own t row (L1/MSHR-merged)
    const vfloat4* hb = (const vfloat4*)(h + (size_t)row * DDIM) + lane;
    const vfloat4* rb = (const vfloat4*)(r + (size_t)row * DDIM) + lane;
    const vfloat4* tb = (const vfloat4*)(t + (size_t)row * DDIM) + lane;
    const vfloat4* nb = (rl == 1) ? tb
                       : (const vfloat4*)(t + (size_t)nidx * DDIM) + lane;

    // Issue all 16 loads (chunk-major so consumption order == issue order;
    // compute on chunk c leaves chunks c+1.. still outstanding).
    vfloat4 hv[4], rv[4], tv[4], nv[4];
#pragma unroll
    for (int c = 0; c < 4; ++c) {
        hv[c] = hb[c << 6];
        rv[c] = rb[c << 6];
        tv[c] = tb[c << 6];
        nv[c] = nb[c << 6];
    }
    // keep the compute below from being hoisted between the load issues
    __builtin_amdgcn_sched_barrier(0);

    float psum = 0.0f, nsum = 0.0f;
#pragma unroll
    for (int c = 0; c < 4; ++c) {
        vfloat4 a = hv[c] + rv[c];
        vfloat4 d = a - tv[c];
        vfloat4 e = a - nv[c];
        psum += d.x * d.x + d.y * d.y + d.z * d.z + d.w * d.w;
        nsum += e.x * e.x + e.y * e.y + e.z * e.z + e.w * e.w;
    }

    // wave-64 butterfly reduction
#pragma unroll
    for (int off = 32; off > 0; off >>= 1) {
        psum += __shfl_down(psum, off, 64);
        nsum += __shfl_down(nsum, off, 64);
    }

    if (lane == 0) {
        float pos  = sqrtf(psum);
        float negd = sqrtf(nsum);
        float loss;
        if (rl == 1) loss = fmaxf(0.6f - pos, 0.0f) + 0.5f * expf(-pos);
        else         loss = fmaxf(pos - negd + 0.3f, 0.0f)
                          + 0.3f * fmaxf(0.1f - pos, 0.0f);
        sm[wave] = loss;
    }
    __syncthreads();
    if (threadIdx.x == 0) {
        float blk = (sm[0] + sm[1] + sm[2] + sm[3]) * (1.0f / (float)BDIM);
        atomicAdd(out, blk);   // device-scope by default on CDNA
    }
}

extern "C" void kernel_launch(void* const* d_in, const int* in_sizes, int n_in,
                              void* d_out, int out_size, void* d_ws, size_t ws_size,
                              hipStream_t stream) {
    const float* h = (const float*)d_in[0];
    const float* t = (const float*)d_in[1];
    const float* r = (const float*)d_in[2];
    const int* rel = (const int*)d_in[3];
    const int* neg = (const int*)d_in[4];
    float* out = (float*)d_out;

    zero_out_kernel<<<1, 1, 0, stream>>>(out);
    triplet_vgpr_kernel<<<BDIM / 4, 256, 0, stream>>>(h, t, r, rel, neg, out);
}

// Round 3
// 202.400 us; speedup vs baseline: 1.0182x; 1.0182x over previous
//
#include <hip/hip_runtime.h>
#include <math.h>

// BioTripletLoss: B=16384 rows, D=1024 fp32.
// pos_dist[i] = ||h[i]+r[i]-t[i]||, neg_dist[i] = ||h[i]+r[i]-t[neg_idx[i]]||
// dissim (rel==1): relu(0.6 - pos) + 0.5*exp(-pos)
// sim:             relu(pos - neg + 0.3) + 0.3*relu(0.1 - pos)
// out = mean(per_sample)
//
// R10 (= R9 resubmit after infra failure, + ws_size guard): kill the
// single-address atomic tail. R7 (LDS-DMA, 30% occ), R8 (VGPR path, 54%
// occ), and L3-resident runs ALL land at 78-81us -> limiter is what every
// version shares: 4096 blocks atomicAdd-ing ONE address, serializing at
// one point of coherence (~47cy/block chipwide = the observed duration).
// Fix: per-block partial -> d_ws[blockIdx.x] (contention-free store),
// then a 1-block reduce kernel sums 4096 floats into out.
// Defensive: if ws_size < 16KB, fall back to the R8 atomic path (no stomp).

#define BDIM 16384
#define DDIM 1024
#define NBLK (BDIM / 4)

typedef float vfloat4 __attribute__((ext_vector_type(4)));

__global__ void zero_out_kernel(float* __restrict__ out) { out[0] = 0.0f; }

template <int USE_WS>
__global__ __launch_bounds__(256, 4) void triplet_partial_kernel(
    const float* __restrict__ h, const float* __restrict__ t,
    const float* __restrict__ r, const int* __restrict__ rel,
    const int* __restrict__ neg, float* __restrict__ sink)
{
    __shared__ float sm[4];

    const int wave = threadIdx.x >> 6;
    const int lane = threadIdx.x & 63;
    const int row  = (blockIdx.x << 2) + wave;

    const int nidx = neg[row];
    const int rl   = rel[row];

    // dissim rows never use neg_dist: alias gather to own t row
    const vfloat4* hb = (const vfloat4*)(h + (size_t)row * DDIM) + lane;
    const vfloat4* rb = (const vfloat4*)(r + (size_t)row * DDIM) + lane;
    const vfloat4* tb = (const vfloat4*)(t + (size_t)row * DDIM) + lane;
    const vfloat4* nb = (rl == 1) ? tb
                       : (const vfloat4*)(t + (size_t)nidx * DDIM) + lane;

    vfloat4 hv[4], rv[4], tv[4], nv[4];
#pragma unroll
    for (int c = 0; c < 4; ++c) {
        hv[c] = hb[c << 6];
        rv[c] = rb[c << 6];
        tv[c] = tb[c << 6];
        nv[c] = nb[c << 6];
    }
    __builtin_amdgcn_sched_barrier(0);

    float psum = 0.0f, nsum = 0.0f;
#pragma unroll
    for (int c = 0; c < 4; ++c) {
        vfloat4 a = hv[c] + rv[c];
        vfloat4 d = a - tv[c];
        vfloat4 e = a - nv[c];
        psum += d.x * d.x + d.y * d.y + d.z * d.z + d.w * d.w;
        nsum += e.x * e.x + e.y * e.y + e.z * e.z + e.w * e.w;
    }

    // wave-64 butterfly reduction
#pragma unroll
    for (int off = 32; off > 0; off >>= 1) {
        psum += __shfl_down(psum, off, 64);
        nsum += __shfl_down(nsum, off, 64);
    }

    if (lane == 0) {
        float pos  = sqrtf(psum);
        float negd = sqrtf(nsum);
        float loss;
        if (rl == 1) loss = fmaxf(0.6f - pos, 0.0f) + 0.5f * expf(-pos);
        else         loss = fmaxf(pos - negd + 0.3f, 0.0f)
                          + 0.3f * fmaxf(0.1f - pos, 0.0f);
        sm[wave] = loss;
    }
    __syncthreads();
    if (threadIdx.x == 0) {
        float blk = sm[0] + sm[1] + sm[2] + sm[3];
        if (USE_WS) {
            sink[blockIdx.x] = blk;            // contention-free partial
        } else {
            atomicAdd(sink, blk * (1.0f / (float)BDIM));  // fallback
        }
    }
}

// 1 block x 1024 threads: sum NBLK=4096 partials, write mean to out.
__global__ __launch_bounds__(1024) void reduce_partials_kernel(
    const float* __restrict__ ws, float* __restrict__ out)
{
    __shared__ float sm[16];
    const int tid  = threadIdx.x;
    const int wave = tid >> 6;
    const int lane = tid & 63;

    vfloat4 v = ((const vfloat4*)ws)[tid];   // 4 floats per thread
    float s = v.x + v.y + v.z + v.w;

#pragma unroll
    for (int off = 32; off > 0; off >>= 1)
        s += __shfl_down(s, off, 64);

    if (lane == 0) sm[wave] = s;
    __syncthreads();
    if (tid == 0) {
        float tot = 0.0f;
#pragma unroll
        for (int w = 0; w < 16; ++w) tot += sm[w];
        out[0] = tot * (1.0f / (float)BDIM);
    }
}

extern "C" void kernel_launch(void* const* d_in, const int* in_sizes, int n_in,
                              void* d_out, int out_size, void* d_ws, size_t ws_size,
                              hipStream_t stream) {
    const float* h = (const float*)d_in[0];
    const float* t = (const float*)d_in[1];
    const float* r = (const float*)d_in[2];
    const int* rel = (const int*)d_in[3];
    const int* neg = (const int*)d_in[4];
    float* out = (float*)d_out;
    float* ws  = (float*)d_ws;   // need NBLK floats = 16 KB

    if (ws != nullptr && ws_size >= NBLK * sizeof(float)) {
        triplet_partial_kernel<1><<<NBLK, 256, 0, stream>>>(h, t, r, rel, neg, ws);
        reduce_partials_kernel<<<1, 1024, 0, stream>>>(ws, out);
    } else {
        zero_out_kernel<<<1, 1, 0, stream>>>(out);
        triplet_partial_kernel<0><<<NBLK, 256, 0, stream>>>(h, t, r, rel, neg, out);
    }
}